// Round 7
// baseline (422.796 us; speedup 1.0000x reference)
//
#include <hip/hip_runtime.h>
#include <hip/hip_bf16.h>

#define N_NODES 50000
#define N_EDGES 600000
#define F_IN    92
#define KPAD    96
#define HID     32
#define HEADS   8
#define D1      256
#define G_GRAPHS 512
#define EPSV    1e-5f
#define NCHUNK  49   // ceil(50000/1024)

using short8 = __attribute__((ext_vector_type(8))) short;
using f32x4  = __attribute__((ext_vector_type(4))) float;

__device__ __forceinline__ float bf2f(unsigned short u) {
    return __uint_as_float(((unsigned)u) << 16);
}
__device__ __forceinline__ unsigned short f2bf(float f) {
    unsigned u = __float_as_uint(f);
    return (unsigned short)((u + 0x7FFFu + ((u >> 16) & 1u)) >> 16);  // RNE
}

// ---------------- CSR build ----------------

__global__ void k_deg(const int* __restrict__ ei, const float* __restrict__ ea,
                      int* __restrict__ deg, float* __restrict__ easum) {
    int e = blockIdx.x * 256 + threadIdx.x;
    if (e < N_EDGES) {
        int d = ei[N_EDGES + e];
        atomicAdd(&deg[d], 1);
        atomicAdd(&easum[d], ea[e]);
    }
}

__global__ void k_partial(const int* __restrict__ deg, int* __restrict__ partials) {
    int b = blockIdx.x;
    int s = 0;
    for (int j = 0; j < 4; ++j) {
        int i = b * 1024 + j * 256 + threadIdx.x;
        if (i < N_NODES) s += deg[i];
    }
    for (int off = 32; off; off >>= 1) s += __shfl_down(s, off, 64);
    __shared__ int sm[4];
    if ((threadIdx.x & 63) == 0) sm[threadIdx.x >> 6] = s;
    __syncthreads();
    if (threadIdx.x == 0) partials[b] = sm[0] + sm[1] + sm[2] + sm[3];
}

__global__ void k_scanp(const int* __restrict__ partials, int* __restrict__ poff) {
    if (threadIdx.x == 0 && blockIdx.x == 0) {
        int acc = 0;
        for (int b = 0; b < NCHUNK; ++b) { poff[b] = acc; acc += partials[b]; }
    }
}

__global__ void k_scanc(const int* __restrict__ deg, const int* __restrict__ poff,
                        int* __restrict__ row_off, int* __restrict__ cursor) {
    int b = blockIdx.x;
    int t = threadIdx.x;
    int base_i = b * 1024 + t * 4;
    int v[4]; int s = 0;
    #pragma unroll
    for (int j = 0; j < 4; ++j) {
        int i = base_i + j;
        v[j] = (i < N_NODES) ? deg[i] : 0;
        s += v[j];
    }
    __shared__ int sm[256];
    sm[t] = s;
    __syncthreads();
    int val = s;
    for (int off = 1; off < 256; off <<= 1) {
        int add = (t >= off) ? sm[t - off] : 0;
        __syncthreads();
        val += add;
        sm[t] = val;
        __syncthreads();
    }
    int base = poff[b] + (val - s);   // exclusive prefix
    #pragma unroll
    for (int j = 0; j < 4; ++j) {
        int i = base_i + j;
        if (i < N_NODES) { row_off[i] = base; cursor[i] = base; }
        base += v[j];
    }
}

__global__ void k_fill(const int* __restrict__ ei, const float* __restrict__ ea,
                       int* __restrict__ cursor, int* __restrict__ adj_src,
                       int* __restrict__ adj_dst, float* __restrict__ adj_ea) {
    int e = blockIdx.x * 256 + threadIdx.x;
    if (e < N_EDGES) {
        int d = ei[N_EDGES + e];
        int pos = atomicAdd(&cursor[d], 1);
        adj_src[pos] = ei[e];
        adj_dst[pos] = d;
        adj_ea[pos] = ea[e];
    }
}

__global__ void k_prep(const float* __restrict__ We1, const float* __restrict__ ae1,
                       const float* __restrict__ We2, const float* __restrict__ ae2,
                       float* __restrict__ wedot) {
    int t = threadIdx.x;
    if (t < HEADS) {
        float a = 0.f;
        for (int c = 0; c < HID; ++c) a += We1[t * HID + c] * ae1[t * HID + c];
        wedot[t] = a;
    } else if (t == HEADS) {
        float a = 0.f;
        for (int c = 0; c < HID; ++c) a += We2[c] * ae2[c];
        wedot[HEADS] = a;
    }
}

// va[which][h][k] = sum_c W1[k, h*32+c] * a_{s,d}[h*32+c]   (al_1 = x @ va)
__global__ void k_va(const float* __restrict__ W1, const float* __restrict__ as1,
                     const float* __restrict__ ad1, float* __restrict__ va) {
    int gid = blockIdx.x * 256 + threadIdx.x;
    if (gid >= 2 * HEADS * F_IN) return;
    int which = gid / (HEADS * F_IN), rem = gid % (HEADS * F_IN);
    int h = rem / F_IN, k = rem % F_IN;
    const float* av = which ? ad1 : as1;
    float s = 0.f;
    #pragma unroll 8
    for (int c = 0; c < HID; ++c) s += W1[k * D1 + h * HID + c] * av[h * HID + c];
    va[gid] = s;
}

// pack W1 (92x256 f32, zero-pad K to 96) into bf16 MFMA-B fragment order
__global__ void k_packW1(const float* __restrict__ W1, unsigned short* __restrict__ W1p) {
    int gid = blockIdx.x * 256 + threadIdx.x;
    if (gid >= KPAD * D1) return;
    int k = gid >> 8, col = gid & 255;
    unsigned short v = 0;
    if (k < F_IN) v = f2bf(W1[k * D1 + col]);
    W1p[(((k >> 3) * D1) + col) * 8 + (k & 7)] = v;
}

// pack W2 (256x32 f32) into bf16 MFMA-B fragment order
__global__ void k_packW2(const float* __restrict__ W2, unsigned short* __restrict__ W2p) {
    int i = blockIdx.x * 256 + threadIdx.x;   // i = k*32 + col
    if (i >= D1 * HID) return;
    int k = i >> 5, col = i & 31;
    W2p[(((k >> 3) * 32) + col) * 8 + (k & 7)] = f2bf(W2[i]);
}

// ---------------- conv1 ----------------

// x -> xb (bf16, K padded to 96) + exact f32 attention logits via va.
// Block: 16 nodes.
__global__ __launch_bounds__(256) void k_xba(const float* __restrict__ x,
                                             const float* __restrict__ va,
                                             unsigned short* __restrict__ xb,
                                             float* __restrict__ al_s,
                                             float* __restrict__ al_d) {
    __shared__ float xs[16 * F_IN];
    int n0 = blockIdx.x * 16;
    for (int i = threadIdx.x; i < 16 * F_IN; i += 256)
        xs[i] = x[(size_t)n0 * F_IN + i];
    __syncthreads();
    for (int i = threadIdx.x; i < 16 * KPAD; i += 256) {
        int r = i / KPAD, kk = i - r * KPAD;
        unsigned short v = 0;
        if (kk < F_IN) v = f2bf(xs[r * F_IN + kk]);
        xb[(size_t)(n0 + r) * KPAD + kk] = v;
    }
    // alpha logits: thread t -> (row t>>4, vec t&15); vec j = which*8 + h
    int t = threadIdx.x;
    int r = t >> 4, j = t & 15;
    const float* vp = va + j * F_IN;
    float s = 0.f;
    for (int k = 0; k < F_IN; ++k) s += xs[r * F_IN + k] * vp[k];
    if (j < 8) al_s[(n0 + r) * HEADS + j] = s;
    else       al_d[(n0 + r) * HEADS + (j - 8)] = s;
}

// xb(bf16) @ W1p(bf16) -> h1h (bf16, head-major slices [h][node][32]) via MFMA.
__global__ __launch_bounds__(256) void k_gemm1m(const unsigned short* __restrict__ xb,
                                                const unsigned short* __restrict__ W1p,
                                                unsigned short* __restrict__ h1h) {
    int wid = threadIdx.x >> 6, l = threadIdx.x & 63;
    int n0 = blockIdx.x * 16;
    int g = l >> 4, c16 = l & 15;
    const short8* ap = (const short8*)(xb + (size_t)(n0 + c16) * KPAD + g * 8);
    short8 a0 = ap[0], a1 = ap[4], a2 = ap[8];   // k = g*8 + {0,32,64}
    const short8* wp = (const short8*)W1p;
    #pragma unroll
    for (int ct = 0; ct < 4; ++ct) {
        int col = (wid * 4 + ct) * 16 + c16;
        f32x4 acc = {0.f, 0.f, 0.f, 0.f};
        acc = __builtin_amdgcn_mfma_f32_16x16x32_bf16(a0, wp[(0 * 4 + g) * D1 + col], acc, 0, 0, 0);
        acc = __builtin_amdgcn_mfma_f32_16x16x32_bf16(a1, wp[(1 * 4 + g) * D1 + col], acc, 0, 0, 0);
        acc = __builtin_amdgcn_mfma_f32_16x16x32_bf16(a2, wp[(2 * 4 + g) * D1 + col], acc, 0, 0, 0);
        #pragma unroll
        for (int r = 0; r < 4; ++r) {
            int node = n0 + g * 4 + r;
            h1h[((size_t)(col >> 5) * N_NODES + node) * 32 + (col & 31)] = f2bf(acc[r]);
        }
    }
}

// per-(edge,head) softmax weights for conv1, head-major output w1h[h][e]
__global__ void k_ew1(const int* __restrict__ adj_src, const int* __restrict__ adj_dst,
                      const float* __restrict__ adj_ea, const float* __restrict__ al_s,
                      const float* __restrict__ al_d, const float* __restrict__ wedot,
                      float* __restrict__ w1h) {
    int e = blockIdx.x * 256 + threadIdx.x;
    int h = blockIdx.y;
    if (e >= N_EDGES) return;
    int s = adj_src[e], d = adj_dst[e];
    float a = al_s[s * HEADS + h] + al_d[d * HEADS + h] + adj_ea[e] * wedot[h];
    a = a > 0.f ? a : 0.2f * a;
    w1h[(size_t)h * N_EDGES + e] = __expf(a);
}

// aggregation conv1: one wave per (node, head); head = blockIdx & 7 so each
// XCD works a single 3.2 MB L2-resident slice. 8 edge-slots x 8 ch-lanes.
__global__ __launch_bounds__(512) void k_aggr1(
        const int* __restrict__ row_off, const int* __restrict__ deg,
        const int* __restrict__ adj_src, const float* __restrict__ w1h,
        const float* __restrict__ easum, const unsigned short* __restrict__ h1h,
        const float* __restrict__ al_s, const float* __restrict__ al_d,
        const float* __restrict__ wedot,
        const float* __restrict__ b1, const float* __restrict__ g1,
        const float* __restrict__ be1, const float* __restrict__ m1,
        const float* __restrict__ v1, unsigned short* __restrict__ h1p) {
    int wid = threadIdx.x >> 6, l = threadIdx.x & 63;
    int h = blockIdx.x & 7;
    int n = (blockIdx.x >> 3) * 8 + wid;
    if (n >= N_NODES) return;
    int eslot = l >> 3, cl = l & 7;
    int r0 = row_off[n], cnt = deg[n];
    const float* wrow = w1h + (size_t)h * N_EDGES + r0;
    const int* srow = adj_src + r0;
    const unsigned short* hsl = h1h + (size_t)h * N_NODES * 32;
    float a0 = 0.f, a1 = 0.f, a2 = 0.f, a3 = 0.f, den = 0.f;
    for (int base = 0; base < cnt; base += 64) {
        int m = cnt - base; if (m > 64) m = 64;
        int sl = (l < m) ? srow[base + l] : 0;
        float wl = (l < m) ? wrow[base + l] : 0.f;
        for (int i = 0; i < m; i += 8) {
            int j = i + eslot;
            int jj = j < m ? j : 0;
            int s = __shfl(sl, jj, 64);
            float wj = __shfl(wl, jj, 64);
            if (j < m) {
                den += wj;
                ushort4 p = *(const ushort4*)(hsl + (size_t)s * 32 + cl * 4);
                a0 += wj * bf2f(p.x); a1 += wj * bf2f(p.y);
                a2 += wj * bf2f(p.z); a3 += wj * bf2f(p.w);
            }
        }
    }
    // reduce across the 8 edge-slots (cl stays fixed)
    #pragma unroll
    for (int off = 8; off < 64; off <<= 1) {
        a0 += __shfl_xor(a0, off, 64);
        a1 += __shfl_xor(a1, off, 64);
        a2 += __shfl_xor(a2, off, 64);
        a3 += __shfl_xor(a3, off, 64);
        den += __shfl_xor(den, off, 64);
    }
    {   // self loop, attr = mean of incoming (0 if none)
        float la = easum[n] / (float)(cnt > 0 ? cnt : 1);
        float a = al_s[n * HEADS + h] + al_d[n * HEADS + h] + la * wedot[h];
        a = a > 0.f ? a : 0.2f * a;
        float w = __expf(a);
        den += w;
        ushort4 p = *(const ushort4*)(hsl + (size_t)n * 32 + cl * 4);
        a0 += w * bf2f(p.x); a1 += w * bf2f(p.y);
        a2 += w * bf2f(p.z); a3 += w * bf2f(p.w);
    }
    if (eslot == 0) {
        float inv = 1.f / den;
        int c = h * 32 + cl * 4;
        float acc[4] = {a0, a1, a2, a3};
        ushort4 o;
        unsigned short* po = (unsigned short*)&o;
        #pragma unroll
        for (int j = 0; j < 4; ++j) {
            float ov = acc[j] * inv + b1[c + j];
            float sc = g1[c + j] * __frsqrt_rn(v1[c + j] + EPSV);
            float y = (ov - m1[c + j]) * sc + be1[c + j];
            po[j] = f2bf(y > 0.f ? y : 0.f);
        }
        *(ushort4*)(h1p + (size_t)n * D1 + c) = o;
    }
}

// ---------------- conv2 ----------------

// h1p(bf16) @ W2p(bf16) -> h2b (bf16) via MFMA, fused alpha2.
__global__ __launch_bounds__(256) void k_gemm2(const unsigned short* __restrict__ h1p,
                                               const unsigned short* __restrict__ W2p,
                                               const float* __restrict__ as2,
                                               const float* __restrict__ ad2,
                                               unsigned short* __restrict__ h2b,
                                               float* __restrict__ al_s2,
                                               float* __restrict__ al_d2) {
    int wid = threadIdx.x >> 6, l = threadIdx.x & 63;
    int wave = blockIdx.x * 4 + wid;
    if (wave >= N_NODES / 16) return;
    int n0 = wave * 16;
    int g = l >> 4;        // k-subgroup 0..3
    int c16 = l & 15;      // col within 16 / A-row within 16
    f32x4 acc0 = {0.f, 0.f, 0.f, 0.f};
    f32x4 acc1 = {0.f, 0.f, 0.f, 0.f};
    const short8* ap = (const short8*)(h1p + (size_t)(n0 + c16) * D1 + g * 8);
    const short8* wp = (const short8*)W2p;
    #pragma unroll
    for (int ks = 0; ks < 8; ++ks) {
        short8 afrag = ap[ks * 4];                     // +ks*32 bf16
        short8 b0 = wp[(ks * 4 + g) * 32 + c16];
        short8 b1 = wp[(ks * 4 + g) * 32 + 16 + c16];
        acc0 = __builtin_amdgcn_mfma_f32_16x16x32_bf16(afrag, b0, acc0, 0, 0, 0);
        acc1 = __builtin_amdgcn_mfma_f32_16x16x32_bf16(afrag, b1, acc1, 0, 0, 0);
    }
    // C layout: col = lane&15, row = (lane>>4)*4 + reg
    float s0 = as2[c16], s1 = as2[16 + c16];
    float d0 = ad2[c16], d1 = ad2[16 + c16];
    float ps[4], pd[4];
    #pragma unroll
    for (int r = 0; r < 4; ++r) {
        int node = n0 + g * 4 + r;
        h2b[(size_t)node * HID + c16]      = f2bf(acc0[r]);
        h2b[(size_t)node * HID + 16 + c16] = f2bf(acc1[r]);
        ps[r] = acc0[r] * s0 + acc1[r] * s1;
        pd[r] = acc0[r] * d0 + acc1[r] * d1;
    }
    #pragma unroll
    for (int off = 1; off < 16; off <<= 1) {
        #pragma unroll
        for (int r = 0; r < 4; ++r) {
            ps[r] += __shfl_xor(ps[r], off, 64);
            pd[r] += __shfl_xor(pd[r], off, 64);
        }
    }
    if (c16 == 0) {
        #pragma unroll
        for (int r = 0; r < 4; ++r) {
            int node = n0 + g * 4 + r;
            al_s2[node] = ps[r];
            al_d2[node] = pd[r];
        }
    }
}

// per-edge softmax weights for conv2, CSR order
__global__ void k_ew2(const int* __restrict__ adj_src, const int* __restrict__ adj_dst,
                      const float* __restrict__ adj_ea, const float* __restrict__ al_s2,
                      const float* __restrict__ al_d2, const float* __restrict__ wedot,
                      float* __restrict__ w2) {
    int gid = blockIdx.x * 256 + threadIdx.x;
    if (gid >= N_EDGES) return;
    int s = adj_src[gid], d = adj_dst[gid];
    float a = al_s2[s] + al_d2[d] + adj_ea[gid] * wedot[HEADS];
    a = a > 0.f ? a : 0.2f * a;
    w2[gid] = __expf(a);
}

// aggregation conv2: 1 wave per node, 4 edges/iter (quad-split), bf16 h2 rows.
__global__ __launch_bounds__(256) void k_aggr2(
        const int* __restrict__ row_off, const int* __restrict__ deg,
        const int* __restrict__ adj_src, const float* __restrict__ w2,
        const float* __restrict__ easum, const unsigned short* __restrict__ h2b,
        const float* __restrict__ al_s2, const float* __restrict__ al_d2,
        const float* __restrict__ wedot,
        const float* __restrict__ b2, const float* __restrict__ g2,
        const float* __restrict__ be2, const float* __restrict__ m2,
        const float* __restrict__ v2, float* __restrict__ h2p) {
    int wid = threadIdx.x >> 6, l = threadIdx.x & 63;
    int n = blockIdx.x * 4 + wid;
    if (n >= N_NODES) return;
    int q = l >> 4, c2 = l & 15;          // quad, channel-pair index
    int r0 = row_off[n], cnt = deg[n];
    float acc0 = 0.f, acc1 = 0.f, den = 0.f;
    for (int base = 0; base < cnt; base += 64) {
        int m = cnt - base; if (m > 64) m = 64;
        int sl = (l < m) ? adj_src[r0 + base + l] : 0;
        float wv = (l < m) ? w2[r0 + base + l] : 0.f;
        for (int i = 0; i < m; i += 4) {
            int j = i + q;
            int jj = j < m ? j : 0;
            int s = __shfl(sl, jj, 64);
            float wj = __shfl(wv, jj, 64);
            if (j < m) {
                den += wj;
                ushort2 p = *(const ushort2*)(h2b + (size_t)s * HID + c2 * 2);
                acc0 += wj * bf2f(p.x);
                acc1 += wj * bf2f(p.y);
            }
        }
    }
    // cross-quad reduce (each edge counted by exactly one quad)
    acc0 += __shfl_xor(acc0, 16, 64); acc0 += __shfl_xor(acc0, 32, 64);
    acc1 += __shfl_xor(acc1, 16, 64); acc1 += __shfl_xor(acc1, 32, 64);
    den  += __shfl_xor(den, 16, 64);  den  += __shfl_xor(den, 32, 64);
    {   // self loop (all lanes add once, post-reduction)
        float la = easum[n] / (float)(cnt > 0 ? cnt : 1);
        float a = al_s2[n] + al_d2[n] + la * wedot[HEADS];
        a = a > 0.f ? a : 0.2f * a;
        float w = __expf(a);
        den += w;
        ushort2 p = *(const ushort2*)(h2b + (size_t)n * HID + c2 * 2);
        acc0 += w * bf2f(p.x);
        acc1 += w * bf2f(p.y);
    }
    int c = c2 * 2;
    float inv = 1.f / den;
    float o0 = acc0 * inv + b2[c];
    float o1 = acc1 * inv + b2[c + 1];
    float y0 = (o0 - m2[c]) * (g2[c] * __frsqrt_rn(v2[c] + EPSV)) + be2[c];
    float y1 = (o1 - m2[c + 1]) * (g2[c + 1] * __frsqrt_rn(v2[c + 1] + EPSV)) + be2[c + 1];
    y0 = y0 > 0.f ? y0 : 0.f;
    y1 = y1 > 0.f ? y1 : 0.f;
    if (q == 0) {
        float2 st = {y0, y1};
        *(float2*)(h2p + (size_t)n * HID + c) = st;
    }
}

// pool (mean over sorted batch segments) + fc, one block per graph
__global__ __launch_bounds__(64) void k_poolfc(const float* __restrict__ h2p,
                                               const int* __restrict__ batch,
                                               const float* __restrict__ fcW,
                                               const float* __restrict__ fcb,
                                               float* __restrict__ out) {
    int g = blockIdx.x;
    int l = threadIdx.x;
    auto lb = [&](int key) {
        int lo = 0, hi = N_NODES;
        while (lo < hi) {
            int mid = (lo + hi) >> 1;
            if (batch[mid] < key) lo = mid + 1; else hi = mid;
        }
        return lo;
    };
    int s0 = lb(g), s1 = lb(g + 1);
    int c = l & 31, half = l >> 5;
    float acc = 0.f;
    for (int r = s0 + half; r < s1; r += 2)
        acc += h2p[(size_t)r * HID + c];
    acc += __shfl_xor(acc, 32, 64);
    int cn = s1 - s0;
    float mean = acc / (float)(cn > 0 ? cn : 1);
    float p = mean * fcW[c];
    #pragma unroll
    for (int off = 1; off < 32; off <<= 1) p += __shfl_xor(p, off, 64);
    if (l == 0) out[g] = p + fcb[0];
}

// ---------------- launch ----------------

extern "C" void kernel_launch(void* const* d_in, const int* in_sizes, int n_in,
                              void* d_out, int out_size, void* d_ws, size_t ws_size,
                              hipStream_t stream) {
    const float* x    = (const float*)d_in[0];
    const int*   ei   = (const int*)  d_in[1];
    const float* ea   = (const float*)d_in[2];
    const int*   batch= (const int*)  d_in[3];
    const float* W1   = (const float*)d_in[4];
    const float* We1  = (const float*)d_in[5];
    const float* as1  = (const float*)d_in[6];
    const float* ad1  = (const float*)d_in[7];
    const float* ae1  = (const float*)d_in[8];
    const float* b1   = (const float*)d_in[9];
    const float* g1   = (const float*)d_in[10];
    const float* be1  = (const float*)d_in[11];
    const float* m1   = (const float*)d_in[12];
    const float* v1   = (const float*)d_in[13];
    const float* W2   = (const float*)d_in[14];
    const float* We2  = (const float*)d_in[15];
    const float* as2  = (const float*)d_in[16];
    const float* ad2  = (const float*)d_in[17];
    const float* ae2  = (const float*)d_in[18];
    const float* b2   = (const float*)d_in[19];
    const float* g2   = (const float*)d_in[20];
    const float* be2  = (const float*)d_in[21];
    const float* m2   = (const float*)d_in[22];
    const float* v2   = (const float*)d_in[23];
    const float* fcW  = (const float*)d_in[24];
    const float* fcb  = (const float*)d_in[25];
    float* out = (float*)d_out;

    char* ws = (char*)d_ws;
    size_t off = 0;
    auto alloc = [&](size_t bytes) -> void* {
        void* p = ws + off;
        off += (bytes + 255) & ~(size_t)255;
        return p;
    };
    int*   deg     = (int*)  alloc((size_t)N_NODES * 4);
    float* easum   = (float*)alloc((size_t)N_NODES * 4);
    int*   row_off = (int*)  alloc((size_t)N_NODES * 4);
    int*   cursor  = (int*)  alloc((size_t)N_NODES * 4);
    int*   adj_src = (int*)  alloc((size_t)N_EDGES * 4);
    int*   adj_dst = (int*)  alloc((size_t)N_EDGES * 4);
    float* adj_ea  = (float*)alloc((size_t)N_EDGES * 4);
    float* w1h     = (float*)alloc((size_t)N_EDGES * HEADS * 4);
    float* w2      = (float*)alloc((size_t)N_EDGES * 4);
    float* al_s1   = (float*)alloc((size_t)N_NODES * HEADS * 4);
    float* al_d1   = (float*)alloc((size_t)N_NODES * HEADS * 4);
    float* al_s2   = (float*)alloc((size_t)N_NODES * 4);
    float* al_d2   = (float*)alloc((size_t)N_NODES * 4);
    float* wedot   = (float*)alloc(16 * 4);
    float* va      = (float*)alloc((size_t)2 * HEADS * F_IN * 4);
    int*   partials= (int*)  alloc(64 * 4);
    int*   poff    = (int*)  alloc(64 * 4);
    unsigned short* W1p = (unsigned short*)alloc((size_t)KPAD * D1 * 2);
    unsigned short* W2p = (unsigned short*)alloc((size_t)D1 * HID * 2);
    unsigned short* xb  = (unsigned short*)alloc((size_t)N_NODES * KPAD * 2);
    unsigned short* h1h = (unsigned short*)alloc((size_t)N_NODES * D1 * 2);
    unsigned short* h1p = (unsigned short*)alloc((size_t)N_NODES * D1 * 2);
    unsigned short* h2b = (unsigned short*)alloc((size_t)N_NODES * HID * 2);
    float* h2p     = (float*)alloc((size_t)N_NODES * HID * 4);
    (void)ws_size; (void)in_sizes; (void)n_in; (void)out_size;

    hipMemsetAsync(deg,   0, (size_t)N_NODES * 4, stream);
    hipMemsetAsync(easum, 0, (size_t)N_NODES * 4, stream);

    k_deg<<<(N_EDGES + 255) / 256, 256, 0, stream>>>(ei, ea, deg, easum);
    k_partial<<<NCHUNK, 256, 0, stream>>>(deg, partials);
    k_scanp<<<1, 64, 0, stream>>>(partials, poff);
    k_scanc<<<NCHUNK, 256, 0, stream>>>(deg, poff, row_off, cursor);
    k_fill<<<(N_EDGES + 255) / 256, 256, 0, stream>>>(ei, ea, cursor, adj_src, adj_dst, adj_ea);
    k_prep<<<1, 64, 0, stream>>>(We1, ae1, We2, ae2, wedot);
    k_va<<<(2 * HEADS * F_IN + 255) / 256, 256, 0, stream>>>(W1, as1, ad1, va);
    k_packW1<<<(KPAD * D1 + 255) / 256, 256, 0, stream>>>(W1, W1p);
    k_packW2<<<(D1 * HID + 255) / 256, 256, 0, stream>>>(W2, W2p);

    k_xba<<<N_NODES / 16, 256, 0, stream>>>(x, va, xb, al_s1, al_d1);
    k_gemm1m<<<N_NODES / 16, 256, 0, stream>>>(xb, W1p, h1h);
    {
        dim3 ge((N_EDGES + 255) / 256, HEADS);
        k_ew1<<<ge, 256, 0, stream>>>(adj_src, adj_dst, adj_ea, al_s1, al_d1, wedot, w1h);
    }
    k_aggr1<<<((N_NODES + 7) / 8) * 8, 512, 0, stream>>>(row_off, deg, adj_src, w1h, easum,
                                                         h1h, al_s1, al_d1, wedot, b1, g1, be1,
                                                         m1, v1, h1p);

    k_gemm2<<<(N_NODES / 16 + 3) / 4, 256, 0, stream>>>(h1p, W2p, as2, ad2, h2b, al_s2, al_d2);
    k_ew2<<<(N_EDGES + 255) / 256, 256, 0, stream>>>(adj_src, adj_dst, adj_ea,
                                                     al_s2, al_d2, wedot, w2);
    k_aggr2<<<(N_NODES + 3) / 4, 256, 0, stream>>>(row_off, deg, adj_src, w2, easum,
                                                   h2b, al_s2, al_d2, wedot, b2, g2, be2,
                                                   m2, v2, h2p);
    k_poolfc<<<G_GRAPHS, 64, 0, stream>>>(h2p, batch, fcW, fcb, out);
}

// Round 8
// 277.972 us; speedup vs baseline: 1.5210x; 1.5210x over previous
//
#include <hip/hip_runtime.h>
#include <hip/hip_bf16.h>

#define N_NODES 50000
#define N_EDGES 600000
#define F_IN    92
#define KPAD    96
#define HID     32
#define HEADS   8
#define D1      256
#define G_GRAPHS 512
#define EPSV    1e-5f
#define NCHUNK  49   // ceil(50000/1024)

using short8  = __attribute__((ext_vector_type(8))) short;
using ushort8 = __attribute__((ext_vector_type(8))) unsigned short;
using f32x4   = __attribute__((ext_vector_type(4))) float;

__device__ __forceinline__ float bf2f(unsigned short u) {
    return __uint_as_float(((unsigned)u) << 16);
}
__device__ __forceinline__ unsigned short f2bf(float f) {
    unsigned u = __float_as_uint(f);
    return (unsigned short)((u + 0x7FFFu + ((u >> 16) & 1u)) >> 16);  // RNE
}

// ---------------- CSR build ----------------

__global__ void k_deg(const int* __restrict__ ei, const float* __restrict__ ea,
                      int* __restrict__ deg, float* __restrict__ easum) {
    int e = blockIdx.x * 256 + threadIdx.x;
    if (e < N_EDGES) {
        int d = ei[N_EDGES + e];
        atomicAdd(&deg[d], 1);
        atomicAdd(&easum[d], ea[e]);
    }
}

__global__ void k_partial(const int* __restrict__ deg, int* __restrict__ partials) {
    int b = blockIdx.x;
    int s = 0;
    for (int j = 0; j < 4; ++j) {
        int i = b * 1024 + j * 256 + threadIdx.x;
        if (i < N_NODES) s += deg[i];
    }
    for (int off = 32; off; off >>= 1) s += __shfl_down(s, off, 64);
    __shared__ int sm[4];
    if ((threadIdx.x & 63) == 0) sm[threadIdx.x >> 6] = s;
    __syncthreads();
    if (threadIdx.x == 0) partials[b] = sm[0] + sm[1] + sm[2] + sm[3];
}

__global__ void k_scanp(const int* __restrict__ partials, int* __restrict__ poff) {
    if (threadIdx.x == 0 && blockIdx.x == 0) {
        int acc = 0;
        for (int b = 0; b < NCHUNK; ++b) { poff[b] = acc; acc += partials[b]; }
    }
}

__global__ void k_scanc(const int* __restrict__ deg, const int* __restrict__ poff,
                        int* __restrict__ row_off, int* __restrict__ cursor) {
    int b = blockIdx.x;
    int t = threadIdx.x;
    int base_i = b * 1024 + t * 4;
    int v[4]; int s = 0;
    #pragma unroll
    for (int j = 0; j < 4; ++j) {
        int i = base_i + j;
        v[j] = (i < N_NODES) ? deg[i] : 0;
        s += v[j];
    }
    __shared__ int sm[256];
    sm[t] = s;
    __syncthreads();
    int val = s;
    for (int off = 1; off < 256; off <<= 1) {
        int add = (t >= off) ? sm[t - off] : 0;
        __syncthreads();
        val += add;
        sm[t] = val;
        __syncthreads();
    }
    int base = poff[b] + (val - s);   // exclusive prefix
    #pragma unroll
    for (int j = 0; j < 4; ++j) {
        int i = base_i + j;
        if (i < N_NODES) { row_off[i] = base; cursor[i] = base; }
        base += v[j];
    }
}

__global__ void k_fill(const int* __restrict__ ei, const float* __restrict__ ea,
                       int* __restrict__ cursor, int* __restrict__ adj_src,
                       float* __restrict__ adj_ea) {
    int e = blockIdx.x * 256 + threadIdx.x;
    if (e < N_EDGES) {
        int d = ei[N_EDGES + e];
        int pos = atomicAdd(&cursor[d], 1);
        adj_src[pos] = ei[e];
        adj_ea[pos] = ea[e];
    }
}

// fused setup: packW1 (96 blocks) | packW2 (32) | va (6) | wedot (1)
__global__ void k_setup(const float* __restrict__ W1, const float* __restrict__ W2,
                        const float* __restrict__ We1, const float* __restrict__ ae1,
                        const float* __restrict__ We2, const float* __restrict__ ae2,
                        const float* __restrict__ as1, const float* __restrict__ ad1,
                        unsigned short* __restrict__ W1p, unsigned short* __restrict__ W2p,
                        float* __restrict__ va, float* __restrict__ wedot) {
    int b = blockIdx.x, t = threadIdx.x;
    if (b < 96) {                       // pack W1 (zero-pad K to 96)
        int gid = b * 256 + t;          // covers KPAD*D1 = 24576
        int k = gid >> 8, col = gid & 255;
        unsigned short v = 0;
        if (k < F_IN) v = f2bf(W1[k * D1 + col]);
        W1p[(((k >> 3) * D1) + col) * 8 + (k & 7)] = v;
    } else if (b < 128) {               // pack W2
        int gid = (b - 96) * 256 + t;   // covers 8192
        int k = gid >> 5, col = gid & 31;
        W2p[(((k >> 3) * 32) + col) * 8 + (k & 7)] = f2bf(W2[gid]);
    } else if (b < 134) {               // va
        int gid = (b - 128) * 256 + t;
        if (gid < 2 * HEADS * F_IN) {
            int which = gid / (HEADS * F_IN), rem = gid % (HEADS * F_IN);
            int h = rem / F_IN, k = rem % F_IN;
            const float* av = which ? ad1 : as1;
            float s = 0.f;
            #pragma unroll 8
            for (int c = 0; c < HID; ++c) s += W1[k * D1 + h * HID + c] * av[h * HID + c];
            va[gid] = s;
        }
    } else {                            // wedot
        if (t < HEADS) {
            float a = 0.f;
            for (int c = 0; c < HID; ++c) a += We1[t * HID + c] * ae1[t * HID + c];
            wedot[t] = a;
        } else if (t == HEADS) {
            float a = 0.f;
            for (int c = 0; c < HID; ++c) a += We2[c] * ae2[c];
            wedot[HEADS] = a;
        }
    }
}

// ---------------- conv1: fused x->bf16 frags + MFMA + alpha logits ----------------
// Block = 256 threads (4 waves) on 16 nodes. h1 row-major [node][256] bf16.
__global__ __launch_bounds__(256) void k_conv1(const float* __restrict__ x,
                                               const unsigned short* __restrict__ W1p,
                                               const float* __restrict__ va,
                                               unsigned short* __restrict__ h1,
                                               float* __restrict__ al_s,
                                               float* __restrict__ al_d) {
    __shared__ float xs[16 * F_IN];
    int n0 = blockIdx.x * 16;
    int t = threadIdx.x;
    for (int i = t; i < 16 * F_IN; i += 256)
        xs[i] = x[(size_t)n0 * F_IN + i];
    __syncthreads();
    // exact f32 attention logits: thread t -> (row t>>4, vec t&15)
    {
        int r = t >> 4, j = t & 15;
        const float* vp = va + j * F_IN;
        const float* xr = xs + r * F_IN;
        float s = 0.f;
        for (int k = 0; k < F_IN; ++k) s += xr[k] * vp[k];
        if (j < 8) al_s[(n0 + r) * HEADS + j] = s;
        else       al_d[(n0 + r) * HEADS + (j - 8)] = s;
    }
    // MFMA: wave wid covers cols wid*64..wid*64+63
    int wid = t >> 6, l = t & 63;
    int g = l >> 4, c16 = l & 15;
    const float* xrow = xs + c16 * F_IN;
    short8 af0, af1, af2;
    #pragma unroll
    for (int j = 0; j < 8; ++j) {
        int k0 = g * 8 + j;
        af0[j] = (short)f2bf(xrow[k0]);                 // k < 32, always valid
        af1[j] = (short)f2bf(xrow[32 + k0]);            // k < 64, valid
        int k2 = 64 + k0;
        af2[j] = (k2 < F_IN) ? (short)f2bf(xrow[k2]) : (short)0;
    }
    const short8* wp = (const short8*)W1p;
    #pragma unroll
    for (int ct = 0; ct < 4; ++ct) {
        int col = (wid * 4 + ct) * 16 + c16;
        f32x4 acc = {0.f, 0.f, 0.f, 0.f};
        acc = __builtin_amdgcn_mfma_f32_16x16x32_bf16(af0, wp[(0 * 4 + g) * D1 + col], acc, 0, 0, 0);
        acc = __builtin_amdgcn_mfma_f32_16x16x32_bf16(af1, wp[(1 * 4 + g) * D1 + col], acc, 0, 0, 0);
        acc = __builtin_amdgcn_mfma_f32_16x16x32_bf16(af2, wp[(2 * 4 + g) * D1 + col], acc, 0, 0, 0);
        #pragma unroll
        for (int r = 0; r < 4; ++r)
            h1[(size_t)(n0 + g * 4 + r) * D1 + col] = f2bf(acc[r]);
    }
}

// ---------------- aggregation conv1 ----------------
// 1 wave per node, all 8 heads; 2 edges/iter (half-wave split); lane covers
// 8 channels (ushort8 = 16B gather); alpha+exp inline.
__global__ __launch_bounds__(256) void k_aggr1(
        const int* __restrict__ row_off, const int* __restrict__ deg,
        const int* __restrict__ adj_src, const float* __restrict__ adj_ea,
        const float* __restrict__ easum, const unsigned short* __restrict__ h1,
        const float* __restrict__ al_s, const float* __restrict__ al_d,
        const float* __restrict__ wedot,
        const float* __restrict__ b1, const float* __restrict__ g1,
        const float* __restrict__ be1, const float* __restrict__ m1,
        const float* __restrict__ v1, unsigned short* __restrict__ h1p) {
    int wid = threadIdx.x >> 6, l = threadIdx.x & 63;
    int n = blockIdx.x * 4 + wid;
    if (n >= N_NODES) return;
    int half = l >> 5, cl = l & 31;     // channels 8*cl..8*cl+7, head cl>>2
    int h = cl >> 2;
    float wd = wedot[h];
    float dn = al_d[n * HEADS + h];
    int r0 = row_off[n], cnt = deg[n];
    float acc[8] = {0.f, 0.f, 0.f, 0.f, 0.f, 0.f, 0.f, 0.f};
    float den = 0.f;
    for (int base = 0; base < cnt; base += 64) {
        int m = cnt - base; if (m > 64) m = 64;
        int sl = 0; float el = 0.f;
        if (l < m) {
            sl = adj_src[r0 + base + l];
            el = adj_ea[r0 + base + l];
        }
        for (int i = 0; i < m; i += 2) {
            int j = i + half;
            int jj = j < m ? j : 0;
            int s = __shfl(sl, jj, 64);
            float eav = __shfl(el, jj, 64);
            if (j < m) {
                float a = al_s[s * HEADS + h] + dn + eav * wd;
                a = a > 0.f ? a : 0.2f * a;
                float w = __expf(a);
                den += w;
                ushort8 p = *(const ushort8*)(h1 + (size_t)s * D1 + cl * 8);
                #pragma unroll
                for (int q = 0; q < 8; ++q) acc[q] += w * bf2f(p[q]);
            }
        }
    }
    // merge half-waves
    #pragma unroll
    for (int q = 0; q < 8; ++q) acc[q] += __shfl_xor(acc[q], 32, 64);
    den += __shfl_xor(den, 32, 64);
    {   // self loop (both halves add identically; only half 0 stores)
        float la = easum[n] / (float)(cnt > 0 ? cnt : 1);
        float a = al_s[n * HEADS + h] + dn + la * wd;
        a = a > 0.f ? a : 0.2f * a;
        float w = __expf(a);
        den += w;
        ushort8 p = *(const ushort8*)(h1 + (size_t)n * D1 + cl * 8);
        #pragma unroll
        for (int q = 0; q < 8; ++q) acc[q] += w * bf2f(p[q]);
    }
    if (half == 0) {
        float inv = 1.f / den;
        int c = cl * 8;
        ushort8 o;
        #pragma unroll
        for (int q = 0; q < 8; ++q) {
            float ov = acc[q] * inv + b1[c + q];
            float sc = g1[c + q] * __frsqrt_rn(v1[c + q] + EPSV);
            float y = (ov - m1[c + q]) * sc + be1[c + q];
            o[q] = f2bf(y > 0.f ? y : 0.f);
        }
        *(ushort8*)(h1p + (size_t)n * D1 + c) = o;
    }
}

// ---------------- conv2 ----------------

// h1p(bf16) @ W2p(bf16) -> h2b (bf16) via MFMA, fused alpha2.
__global__ __launch_bounds__(256) void k_gemm2(const unsigned short* __restrict__ h1p,
                                               const unsigned short* __restrict__ W2p,
                                               const float* __restrict__ as2,
                                               const float* __restrict__ ad2,
                                               unsigned short* __restrict__ h2b,
                                               float* __restrict__ al_s2,
                                               float* __restrict__ al_d2) {
    int wid = threadIdx.x >> 6, l = threadIdx.x & 63;
    int wave = blockIdx.x * 4 + wid;
    if (wave >= N_NODES / 16) return;
    int n0 = wave * 16;
    int g = l >> 4;        // k-subgroup 0..3
    int c16 = l & 15;      // col within 16 / A-row within 16
    f32x4 acc0 = {0.f, 0.f, 0.f, 0.f};
    f32x4 acc1 = {0.f, 0.f, 0.f, 0.f};
    const short8* ap = (const short8*)(h1p + (size_t)(n0 + c16) * D1 + g * 8);
    const short8* wp = (const short8*)W2p;
    #pragma unroll
    for (int ks = 0; ks < 8; ++ks) {
        short8 afrag = ap[ks * 4];                     // +ks*32 bf16
        short8 b0 = wp[(ks * 4 + g) * 32 + c16];
        short8 b1 = wp[(ks * 4 + g) * 32 + 16 + c16];
        acc0 = __builtin_amdgcn_mfma_f32_16x16x32_bf16(afrag, b0, acc0, 0, 0, 0);
        acc1 = __builtin_amdgcn_mfma_f32_16x16x32_bf16(afrag, b1, acc1, 0, 0, 0);
    }
    // C layout: col = lane&15, row = (lane>>4)*4 + reg
    float s0 = as2[c16], s1 = as2[16 + c16];
    float d0 = ad2[c16], d1 = ad2[16 + c16];
    float ps[4], pd[4];
    #pragma unroll
    for (int r = 0; r < 4; ++r) {
        int node = n0 + g * 4 + r;
        h2b[(size_t)node * HID + c16]      = f2bf(acc0[r]);
        h2b[(size_t)node * HID + 16 + c16] = f2bf(acc1[r]);
        ps[r] = acc0[r] * s0 + acc1[r] * s1;
        pd[r] = acc0[r] * d0 + acc1[r] * d1;
    }
    #pragma unroll
    for (int off = 1; off < 16; off <<= 1) {
        #pragma unroll
        for (int r = 0; r < 4; ++r) {
            ps[r] += __shfl_xor(ps[r], off, 64);
            pd[r] += __shfl_xor(pd[r], off, 64);
        }
    }
    if (c16 == 0) {
        #pragma unroll
        for (int r = 0; r < 4; ++r) {
            int node = n0 + g * 4 + r;
            al_s2[node] = ps[r];
            al_d2[node] = pd[r];
        }
    }
}

// aggregation conv2: 1 wave per node, 4 edges/iter (quad-split), inline alpha.
__global__ __launch_bounds__(256) void k_aggr2(
        const int* __restrict__ row_off, const int* __restrict__ deg,
        const int* __restrict__ adj_src, const float* __restrict__ adj_ea,
        const float* __restrict__ easum, const unsigned short* __restrict__ h2b,
        const float* __restrict__ al_s2, const float* __restrict__ al_d2,
        const float* __restrict__ wedot,
        const float* __restrict__ b2, const float* __restrict__ g2,
        const float* __restrict__ be2, const float* __restrict__ m2,
        const float* __restrict__ v2, float* __restrict__ h2p) {
    int wid = threadIdx.x >> 6, l = threadIdx.x & 63;
    int n = blockIdx.x * 4 + wid;
    if (n >= N_NODES) return;
    int q = l >> 4, c2 = l & 15;          // quad, channel-pair index
    float wd = wedot[HEADS];
    float dn = al_d2[n];
    int r0 = row_off[n], cnt = deg[n];
    float acc0 = 0.f, acc1 = 0.f, den = 0.f;
    for (int base = 0; base < cnt; base += 64) {
        int m = cnt - base; if (m > 64) m = 64;
        int sl = 0; float el = 0.f;
        if (l < m) {
            sl = adj_src[r0 + base + l];
            el = adj_ea[r0 + base + l];
        }
        for (int i = 0; i < m; i += 4) {
            int j = i + q;
            int jj = j < m ? j : 0;
            int s = __shfl(sl, jj, 64);
            float eav = __shfl(el, jj, 64);
            if (j < m) {
                float a = al_s2[s] + dn + eav * wd;
                a = a > 0.f ? a : 0.2f * a;
                float w = __expf(a);
                den += w;
                ushort2 p = *(const ushort2*)(h2b + (size_t)s * HID + c2 * 2);
                acc0 += w * bf2f(p.x);
                acc1 += w * bf2f(p.y);
            }
        }
    }
    // cross-quad reduce
    acc0 += __shfl_xor(acc0, 16, 64); acc0 += __shfl_xor(acc0, 32, 64);
    acc1 += __shfl_xor(acc1, 16, 64); acc1 += __shfl_xor(acc1, 32, 64);
    den  += __shfl_xor(den, 16, 64);  den  += __shfl_xor(den, 32, 64);
    {   // self loop
        float la = easum[n] / (float)(cnt > 0 ? cnt : 1);
        float a = al_s2[n] + dn + la * wd;
        a = a > 0.f ? a : 0.2f * a;
        float w = __expf(a);
        den += w;
        ushort2 p = *(const ushort2*)(h2b + (size_t)n * HID + c2 * 2);
        acc0 += w * bf2f(p.x);
        acc1 += w * bf2f(p.y);
    }
    int c = c2 * 2;
    float inv = 1.f / den;
    float o0 = acc0 * inv + b2[c];
    float o1 = acc1 * inv + b2[c + 1];
    float y0 = (o0 - m2[c]) * (g2[c] * __frsqrt_rn(v2[c] + EPSV)) + be2[c];
    float y1 = (o1 - m2[c + 1]) * (g2[c + 1] * __frsqrt_rn(v2[c + 1] + EPSV)) + be2[c + 1];
    y0 = y0 > 0.f ? y0 : 0.f;
    y1 = y1 > 0.f ? y1 : 0.f;
    if (q == 0) {
        float2 st = {y0, y1};
        *(float2*)(h2p + (size_t)n * HID + c) = st;
    }
}

// pool (mean over sorted batch segments) + fc, one block per graph
__global__ __launch_bounds__(64) void k_poolfc(const float* __restrict__ h2p,
                                               const int* __restrict__ batch,
                                               const float* __restrict__ fcW,
                                               const float* __restrict__ fcb,
                                               float* __restrict__ out) {
    int g = blockIdx.x;
    int l = threadIdx.x;
    auto lb = [&](int key) {
        int lo = 0, hi = N_NODES;
        while (lo < hi) {
            int mid = (lo + hi) >> 1;
            if (batch[mid] < key) lo = mid + 1; else hi = mid;
        }
        return lo;
    };
    int s0 = lb(g), s1 = lb(g + 1);
    int c = l & 31, half = l >> 5;
    float acc = 0.f;
    for (int r = s0 + half; r < s1; r += 2)
        acc += h2p[(size_t)r * HID + c];
    acc += __shfl_xor(acc, 32, 64);
    int cn = s1 - s0;
    float mean = acc / (float)(cn > 0 ? cn : 1);
    float p = mean * fcW[c];
    #pragma unroll
    for (int off = 1; off < 32; off <<= 1) p += __shfl_xor(p, off, 64);
    if (l == 0) out[g] = p + fcb[0];
}

// ---------------- launch ----------------

extern "C" void kernel_launch(void* const* d_in, const int* in_sizes, int n_in,
                              void* d_out, int out_size, void* d_ws, size_t ws_size,
                              hipStream_t stream) {
    const float* x    = (const float*)d_in[0];
    const int*   ei   = (const int*)  d_in[1];
    const float* ea   = (const float*)d_in[2];
    const int*   batch= (const int*)  d_in[3];
    const float* W1   = (const float*)d_in[4];
    const float* We1  = (const float*)d_in[5];
    const float* as1  = (const float*)d_in[6];
    const float* ad1  = (const float*)d_in[7];
    const float* ae1  = (const float*)d_in[8];
    const float* b1   = (const float*)d_in[9];
    const float* g1   = (const float*)d_in[10];
    const float* be1  = (const float*)d_in[11];
    const float* m1   = (const float*)d_in[12];
    const float* v1   = (const float*)d_in[13];
    const float* W2   = (const float*)d_in[14];
    const float* We2  = (const float*)d_in[15];
    const float* as2  = (const float*)d_in[16];
    const float* ad2  = (const float*)d_in[17];
    const float* ae2  = (const float*)d_in[18];
    const float* b2   = (const float*)d_in[19];
    const float* g2   = (const float*)d_in[20];
    const float* be2  = (const float*)d_in[21];
    const float* m2   = (const float*)d_in[22];
    const float* v2   = (const float*)d_in[23];
    const float* fcW  = (const float*)d_in[24];
    const float* fcb  = (const float*)d_in[25];
    float* out = (float*)d_out;

    char* ws = (char*)d_ws;
    size_t off = 0;
    auto alloc = [&](size_t bytes) -> void* {
        void* p = ws + off;
        off += (bytes + 255) & ~(size_t)255;
        return p;
    };
    int*   deg     = (int*)  alloc((size_t)N_NODES * 4);
    float* easum   = (float*)alloc((size_t)N_NODES * 4);
    int*   row_off = (int*)  alloc((size_t)N_NODES * 4);
    int*   cursor  = (int*)  alloc((size_t)N_NODES * 4);
    int*   adj_src = (int*)  alloc((size_t)N_EDGES * 4);
    float* adj_ea  = (float*)alloc((size_t)N_EDGES * 4);
    float* al_s1   = (float*)alloc((size_t)N_NODES * HEADS * 4);
    float* al_d1   = (float*)alloc((size_t)N_NODES * HEADS * 4);
    float* al_s2   = (float*)alloc((size_t)N_NODES * 4);
    float* al_d2   = (float*)alloc((size_t)N_NODES * 4);
    float* wedot   = (float*)alloc(16 * 4);
    float* va      = (float*)alloc((size_t)2 * HEADS * F_IN * 4);
    int*   partials= (int*)  alloc(64 * 4);
    int*   poff    = (int*)  alloc(64 * 4);
    unsigned short* W1p = (unsigned short*)alloc((size_t)KPAD * D1 * 2);
    unsigned short* W2p = (unsigned short*)alloc((size_t)D1 * HID * 2);
    unsigned short* h1  = (unsigned short*)alloc((size_t)N_NODES * D1 * 2);
    unsigned short* h1p = (unsigned short*)alloc((size_t)N_NODES * D1 * 2);
    unsigned short* h2b = (unsigned short*)alloc((size_t)N_NODES * HID * 2);
    float* h2p     = (float*)alloc((size_t)N_NODES * HID * 4);
    (void)ws_size; (void)in_sizes; (void)n_in; (void)out_size;

    hipMemsetAsync(deg,   0, (size_t)N_NODES * 4, stream);
    hipMemsetAsync(easum, 0, (size_t)N_NODES * 4, stream);

    k_deg<<<(N_EDGES + 255) / 256, 256, 0, stream>>>(ei, ea, deg, easum);
    k_partial<<<NCHUNK, 256, 0, stream>>>(deg, partials);
    k_scanp<<<1, 64, 0, stream>>>(partials, poff);
    k_scanc<<<NCHUNK, 256, 0, stream>>>(deg, poff, row_off, cursor);
    k_fill<<<(N_EDGES + 255) / 256, 256, 0, stream>>>(ei, ea, cursor, adj_src, adj_ea);
    k_setup<<<135, 256, 0, stream>>>(W1, W2, We1, ae1, We2, ae2, as1, ad1,
                                     W1p, W2p, va, wedot);

    k_conv1<<<N_NODES / 16, 256, 0, stream>>>(x, W1p, va, h1, al_s1, al_d1);
    k_aggr1<<<(N_NODES + 3) / 4, 256, 0, stream>>>(row_off, deg, adj_src, adj_ea, easum,
                                                   h1, al_s1, al_d1, wedot, b1, g1, be1,
                                                   m1, v1, h1p);

    k_gemm2<<<(N_NODES / 16 + 3) / 4, 256, 0, stream>>>(h1p, W2p, as2, ad2, h2b, al_s2, al_d2);
    k_aggr2<<<(N_NODES + 3) / 4, 256, 0, stream>>>(row_off, deg, adj_src, adj_ea, easum,
                                                   h2b, al_s2, al_d2, wedot, b2, g2, be2,
                                                   m2, v2, h2p);
    k_poolfc<<<G_GRAPHS, 64, 0, stream>>>(h2p, batch, fcW, fcb, out);
}